// Round 1
// baseline (92.831 us; speedup 1.0000x reference)
//
#include <hip/hip_runtime.h>
#include <math.h>

#define RES   64
#define NPTS  (RES * RES)   // 4096 grid points
#define NB    4             // batches
#define NN    128           // components per batch
#define NP    16            // points per component
#define CHUNKS 32           // chunks of 128 grid points per batch

__global__ __launch_bounds__(128)
void mma_img_kernel(const float* __restrict__ Bs,
                    const float* __restrict__ Ds,
                    float* __restrict__ out) {
    // LDS staging: Bs[b] and Ds[b] are each 128*16*2 = 4096 floats = 16 KB
    __shared__ float sB[NN * NP * 2];
    __shared__ float sD[NN * NP * 2];
    __shared__ float sW2[NN];

    const int b     = blockIdx.x >> 5;   // blockIdx.x / CHUNKS
    const int chunk = blockIdx.x & 31;
    const int tid   = threadIdx.x;       // 0..127

    // ---- stage global -> LDS with float4 (4096 floats = 1024 float4, 128 thr x 8) ----
    const float4* gB = (const float4*)(Bs + (size_t)b * NN * NP * 2);
    const float4* gD = (const float4*)(Ds + (size_t)b * NN * NP * 2);
    float4* s4B = (float4*)sB;
    float4* s4D = (float4*)sD;
    #pragma unroll
    for (int k = 0; k < 8; ++k) {
        s4B[tid + 128 * k] = gB[tid + 128 * k];
        s4D[tid + 128 * k] = gD[tid + 128 * k];
    }
    __syncthreads();

    // ---- w2[n]: one n per thread ----
    // w[n] = max_{i,j} relu(min(Ds[n,j,0]-Bs[n,i,0], Ds[n,j,1]-Bs[n,i,1]))
    {
        const int n = tid;
        const float* Bn = sB + n * NP * 2;
        const float* Dn = sD + n * NP * 2;
        float w = 0.0f;   // all pw >= 0 (relu), so 0 is a valid identity
        #pragma unroll
        for (int j = 0; j < NP; ++j) {
            const float d0 = Dn[2 * j];
            const float d1 = Dn[2 * j + 1];
            #pragma unroll
            for (int i = 0; i < NP; ++i) {
                float m = fminf(d0 - Bn[2 * i], d1 - Bn[2 * i + 1]);
                m = fmaxf(m, 0.0f);
                w = fmaxf(w, m);
            }
        }
        if (!isfinite(w)) w = 0.0f;
        sW2[n] = w * w;
    }
    __syncthreads();

    // ---- per-grid-point accumulation over n ----
    const int p  = chunk * 128 + tid;    // 0..4095
    const int i0 = p >> 6;               // row index (x0), 'ij' meshgrid, row-major ravel
    const int i1 = p & 63;               // col index (x1)
    const float x0 = -3.0f + 6.0f * (float)i0 / 63.0f;
    const float x1 = -3.0f + 6.0f * (float)i1 / 63.0f;

    const float c = -0.5f / (0.3f * 0.3f);   // -0.5 / BW^2
    float acc = 0.0f;

    for (int n = 0; n < NN; ++n) {
        const float* Bn = sB + n * NP * 2;   // broadcast LDS reads (all lanes same addr)
        const float* Dn = sD + n * NP * 2;
        float db = 1e30f, dd = 1e30f;
        #pragma unroll
        for (int i = 0; i < NP; ++i) {
            db = fminf(db, fmaxf(Bn[2 * i]     - x0, Bn[2 * i + 1] - x1));
            dd = fminf(dd, fmaxf(x0 - Dn[2 * i],     x1 - Dn[2 * i + 1]));
        }
        const float dist = fmaxf(db, dd);
        const float r    = fmaxf(dist, 0.0f);
        acc = fmaf(__expf(c * r * r), sW2[n], acc);
    }

    out[(size_t)b * NPTS + p] = acc;
}

extern "C" void kernel_launch(void* const* d_in, const int* in_sizes, int n_in,
                              void* d_out, int out_size, void* d_ws, size_t ws_size,
                              hipStream_t stream) {
    const float* Bs = (const float*)d_in[0];
    const float* Ds = (const float*)d_in[1];
    float* out = (float*)d_out;
    mma_img_kernel<<<dim3(NB * CHUNKS), dim3(128), 0, stream>>>(Bs, Ds, out);
}

// Round 2
// 67.846 us; speedup vs baseline: 1.3683x; 1.3683x over previous
//
#include <hip/hip_runtime.h>
#include <math.h>

#define RES   64
#define NPTS  (RES * RES)   // 4096 grid points
#define NB    4             // batches
#define NN    128           // components per batch
#define NP    16            // points per component

#define PTS_PER_BLK 32      // grid points per block (kernel 2)
#define NCHUNKS     8       // n-chunks per point
#define NPER        (NN / NCHUNKS)   // 16 n per chunk

// ---------------- kernel 1: w2[b,n] = (max_{i,j} relu(min_c(D-B)))^2 ----------------
__global__ __launch_bounds__(256)
void w2_kernel(const float* __restrict__ Bs, const float* __restrict__ Ds,
               float* __restrict__ w2) {
    const int b  = blockIdx.x;
    const int t  = threadIdx.x;
    const int n  = t & 127;
    const int jh = t >> 7;          // 0 or 1: which half of the j range

    const float* Bn = Bs + (size_t)(b * NN + n) * NP * 2;
    const float* Dn = Ds + (size_t)(b * NN + n) * NP * 2;

    float b0[NP], b1[NP];
    #pragma unroll
    for (int i = 0; i < NP; ++i) { b0[i] = Bn[2 * i]; b1[i] = Bn[2 * i + 1]; }

    float w = 0.0f;                  // relu makes 0 a valid identity
    #pragma unroll
    for (int jj = 0; jj < NP / 2; ++jj) {
        const int j = jh * (NP / 2) + jj;
        const float d0 = Dn[2 * j];
        const float d1 = Dn[2 * j + 1];
        #pragma unroll
        for (int i = 0; i < NP; ++i) {
            float m = fminf(d0 - b0[i], d1 - b1[i]);
            w = fmaxf(w, fmaxf(m, 0.0f));
        }
    }

    __shared__ float wp[2][NN];
    wp[jh][n] = w;
    __syncthreads();
    if (t < NN) {
        float wv = fmaxf(wp[0][t], wp[1][t]);
        if (!isfinite(wv)) wv = 0.0f;
        w2[b * NN + t] = wv * wv;
    }
}

// ---------------- kernel 2: img[b,p] = sum_n exp(-0.5*(relu(dist)/BW)^2) * w2[n] ----
__global__ __launch_bounds__(256)
void img_kernel(const float* __restrict__ Bs, const float* __restrict__ Ds,
                const float* __restrict__ w2, float* __restrict__ out) {
    __shared__ float sB[NN * NP * 2];                 // 16 KB
    __shared__ float sD[NN * NP * 2];                 // 16 KB
    __shared__ float sW2[NN];
    __shared__ float psum[NCHUNKS][PTS_PER_BLK + 1];  // +1 pad: conflict-free

    const int b    = blockIdx.x >> 7;   // 4 batches x 128 point-blocks
    const int pblk = blockIdx.x & 127;
    const int t    = threadIdx.x;       // 0..255

    // stage: 1024 float4 per array, 256 threads x 4
    const float4* gB = (const float4*)(Bs + (size_t)b * NN * NP * 2);
    const float4* gD = (const float4*)(Ds + (size_t)b * NN * NP * 2);
    float4* s4B = (float4*)sB;
    float4* s4D = (float4*)sD;
    #pragma unroll
    for (int k = 0; k < 4; ++k) {
        s4B[t + 256 * k] = gB[t + 256 * k];
        s4D[t + 256 * k] = gD[t + 256 * k];
    }
    if (t < NN) sW2[t] = w2[b * NN + t];
    __syncthreads();

    const int point = t & 31;           // grid point within block
    const int chunk = t >> 5;           // which n-chunk this thread reduces
    const int p  = pblk * PTS_PER_BLK + point;
    const int i0 = p >> 6;              // 'ij' meshgrid, row-major ravel
    const int i1 = p & 63;
    const float x0 = -3.0f + 6.0f * (float)i0 / 63.0f;
    const float x1 = -3.0f + 6.0f * (float)i1 / 63.0f;
    const float c  = -0.5f / (0.3f * 0.3f);

    float acc = 0.0f;
    #pragma unroll 2
    for (int nn = 0; nn < NPER; ++nn) {
        const int n = chunk * NPER + nn;
        const float* Bn = sB + n * NP * 2;   // 2-address broadcast per wave: free
        const float* Dn = sD + n * NP * 2;
        float db = 1e30f, dd = 1e30f;
        #pragma unroll
        for (int i = 0; i < NP; ++i) {
            db = fminf(db, fmaxf(Bn[2 * i]     - x0, Bn[2 * i + 1] - x1));
            dd = fminf(dd, fmaxf(x0 - Dn[2 * i],     x1 - Dn[2 * i + 1]));
        }
        const float r = fmaxf(fmaxf(db, dd), 0.0f);
        acc = fmaf(__expf(c * r * r), sW2[n], acc);
    }

    psum[chunk][point] = acc;
    __syncthreads();
    if (t < PTS_PER_BLK) {
        float s = 0.0f;
        #pragma unroll
        for (int cc = 0; cc < NCHUNKS; ++cc) s += psum[cc][t];
        out[(size_t)b * NPTS + pblk * PTS_PER_BLK + t] = s;
    }
}

extern "C" void kernel_launch(void* const* d_in, const int* in_sizes, int n_in,
                              void* d_out, int out_size, void* d_ws, size_t ws_size,
                              hipStream_t stream) {
    const float* Bs = (const float*)d_in[0];
    const float* Ds = (const float*)d_in[1];
    float* out = (float*)d_out;
    float* w2  = (float*)d_ws;   // NB*NN floats = 2 KB scratch

    w2_kernel<<<dim3(NB), dim3(256), 0, stream>>>(Bs, Ds, w2);
    img_kernel<<<dim3(NB * (NPTS / PTS_PER_BLK)), dim3(256), 0, stream>>>(Bs, Ds, w2, out);
}

// Round 3
// 63.877 us; speedup vs baseline: 1.4533x; 1.0621x over previous
//
#include <hip/hip_runtime.h>
#include <math.h>

#define RES   64
#define NPTS  (RES * RES)   // 4096 grid points
#define NB    4             // batches
#define NN    128           // components per batch
#define NP    16            // points per component
#define STRIDE 36           // padded floats per component in LDS (144 B, 16B-aligned;
                            // interleaved n = c + 32k puts the 8 concurrent b128 reads
                            // of a wave on 8 distinct 4-bank groups -> conflict-free)
#define PTS_PER_BLK 32      // one block = half a grid row (uniform x0)
#define NCHUNK 32           // n-chunks; each thread owns 4 interleaved n

// ---------------- kernel 1: w2[b,n] = (max_{i,j} relu(min_c(D-B)))^2 ----------------
__global__ __launch_bounds__(256)
void w2_kernel(const float* __restrict__ Bs, const float* __restrict__ Ds,
               float* __restrict__ w2) {
    const int b  = blockIdx.x;
    const int t  = threadIdx.x;
    const int n  = t & 127;
    const int jh = t >> 7;          // 0 or 1: which half of the j range

    const float* Bn = Bs + (size_t)(b * NN + n) * NP * 2;
    const float* Dn = Ds + (size_t)(b * NN + n) * NP * 2;

    float b0[NP], b1[NP];
    #pragma unroll
    for (int i = 0; i < NP; ++i) { b0[i] = Bn[2 * i]; b1[i] = Bn[2 * i + 1]; }

    float w = 0.0f;                  // relu makes 0 a valid identity
    #pragma unroll
    for (int jj = 0; jj < NP / 2; ++jj) {
        const int j = jh * (NP / 2) + jj;
        const float d0 = Dn[2 * j];
        const float d1 = Dn[2 * j + 1];
        #pragma unroll
        for (int i = 0; i < NP; ++i) {
            float m = fminf(d0 - b0[i], d1 - b1[i]);
            w = fmaxf(w, fmaxf(m, 0.0f));
        }
    }

    __shared__ float wp[2][NN];
    wp[jh][n] = w;
    __syncthreads();
    if (t < NN) {
        float wv = fmaxf(wp[0][t], wp[1][t]);
        if (!isfinite(wv)) wv = 0.0f;
        w2[b * NN + t] = wv * wv;
    }
}

// ---------------- kernel 2: img[b,p] = sum_n exp(-0.5*(relu(dist)/BW)^2) * w2[n] ----
__global__ __launch_bounds__(256)
void img_kernel(const float* __restrict__ Bs, const float* __restrict__ Ds,
                const float* __restrict__ w2, float* __restrict__ out) {
    __shared__ __align__(16) float sB[NN * STRIDE];   // 18 KB, padded
    __shared__ __align__(16) float sD[NN * STRIDE];   // 18 KB, padded
    __shared__ float sW2[NN];
    __shared__ float psum[NCHUNK][PTS_PER_BLK + 1];   // +1 pad

    const int b    = blockIdx.x >> 7;   // 4 batches x 128 point-blocks
    const int pblk = blockIdx.x & 127;
    const int t    = threadIdx.x;       // 0..255

    // ---- stage global -> LDS (padded layout): 1024 float4 per array ----
    const float4* gB = (const float4*)(Bs + (size_t)b * NN * NP * 2);
    const float4* gD = (const float4*)(Ds + (size_t)b * NN * NP * 2);
    #pragma unroll
    for (int r = 0; r < 4; ++r) {
        const int m   = t + 256 * r;               // float4 index 0..1023
        const int off = (m >> 3) * STRIDE + (m & 7) * 4;
        *(float4*)(sB + off) = gB[m];
        *(float4*)(sD + off) = gD[m];
    }
    if (t < NN) sW2[t] = w2[b * NN + t];
    __syncthreads();

    // ---- thread mapping: 8 point-groups (4 pts each) x 32 n-chunks (4 n each) ----
    const int g  = t & 7;                   // point group
    const int c  = t >> 3;                  // n-chunk
    const int p0 = pblk * PTS_PER_BLK + 4 * g;
    const int i0 = p0 >> 6;                 // block-uniform row -> uniform x0
    const float x0 = -3.0f + 6.0f * (float)i0 / 63.0f;
    float x1v[4];
    #pragma unroll
    for (int j = 0; j < 4; ++j)
        x1v[j] = -3.0f + 6.0f * (float)((p0 + j) & 63) / 63.0f;

    const float cexp = -0.5f / (0.3f * 0.3f);
    float acc[4] = {0.0f, 0.0f, 0.0f, 0.0f};

    for (int k = 0; k < 4; ++k) {
        const int n = c + 32 * k;           // interleaved: wave's 8 chunks -> 8 bank groups
        const float4* B4 = (const float4*)(sB + n * STRIDE);
        const float4* D4 = (const float4*)(sD + n * STRIDE);
        float db[4] = {1e30f, 1e30f, 1e30f, 1e30f};
        float dd[4] = {1e30f, 1e30f, 1e30f, 1e30f};
        #pragma unroll
        for (int q = 0; q < 8; ++q) {       // 2 boundary points per float4
            const float4 fb = B4[q];
            const float4 fd = D4[q];
            float s  = fb.x - x0;           // shared across the 4 grid points
            float sd = x0 - fd.x;
            #pragma unroll
            for (int j = 0; j < 4; ++j) {
                db[j] = fminf(db[j], fmaxf(s,  fb.y - x1v[j]));
                dd[j] = fminf(dd[j], fmaxf(sd, x1v[j] - fd.y));
            }
            s  = fb.z - x0;
            sd = x0 - fd.z;
            #pragma unroll
            for (int j = 0; j < 4; ++j) {
                db[j] = fminf(db[j], fmaxf(s,  fb.w - x1v[j]));
                dd[j] = fminf(dd[j], fmaxf(sd, x1v[j] - fd.w));
            }
        }
        const float w2n = sW2[n];
        #pragma unroll
        for (int j = 0; j < 4; ++j) {
            const float r = fmaxf(fmaxf(db[j], dd[j]), 0.0f);
            acc[j] = fmaf(__expf(cexp * r * r), w2n, acc[j]);
        }
    }

    #pragma unroll
    for (int j = 0; j < 4; ++j) psum[c][4 * g + j] = acc[j];
    __syncthreads();
    if (t < PTS_PER_BLK) {
        float s = 0.0f;
        #pragma unroll
        for (int q = 0; q < NCHUNK; ++q) s += psum[q][t];
        out[(size_t)b * NPTS + pblk * PTS_PER_BLK + t] = s;
    }
}

extern "C" void kernel_launch(void* const* d_in, const int* in_sizes, int n_in,
                              void* d_out, int out_size, void* d_ws, size_t ws_size,
                              hipStream_t stream) {
    const float* Bs = (const float*)d_in[0];
    const float* Ds = (const float*)d_in[1];
    float* out = (float*)d_out;
    float* w2  = (float*)d_ws;   // NB*NN floats = 2 KB scratch

    w2_kernel<<<dim3(NB), dim3(256), 0, stream>>>(Bs, Ds, w2);
    img_kernel<<<dim3(NB * (NPTS / PTS_PER_BLK)), dim3(256), 0, stream>>>(Bs, Ds, w2, out);
}

// Round 4
// 62.360 us; speedup vs baseline: 1.4886x; 1.0243x over previous
//
#include <hip/hip_runtime.h>
#include <math.h>

#define RES   64
#define NPTS  (RES * RES)   // 4096 grid points
#define NB    4             // batches
#define NN    128           // components per batch
#define NP    16            // points per component
#define STRIDE 36           // padded floats per component in LDS (144 B, 16B-aligned;
                            // main loop's 8 concurrent b128 reads/wave -> 8 bank groups)
#define PTS_PER_BLK 32      // one block = half a grid row (uniform x0)
#define NCHUNK 32           // n-chunks; each thread owns 4 interleaved n

// Single fused kernel: stage B/D -> LDS, compute w2[n] in-block, then accumulate img.
__global__ __launch_bounds__(256)
void fused_kernel(const float* __restrict__ Bs, const float* __restrict__ Ds,
                  float* __restrict__ out) {
    __shared__ __align__(16) float sB[NN * STRIDE];   // 18 KB, padded
    __shared__ __align__(16) float sD[NN * STRIDE];   // 18 KB, padded
    __shared__ float sW2[NN];
    __shared__ float wp[2][NN];
    __shared__ float psum[NCHUNK][PTS_PER_BLK + 1];   // +1 pad

    const int b    = blockIdx.x >> 7;   // 4 batches x 128 point-blocks
    const int pblk = blockIdx.x & 127;
    const int t    = threadIdx.x;       // 0..255

    // ---- stage global -> LDS (padded layout): 1024 float4 per array ----
    const float4* gB = (const float4*)(Bs + (size_t)b * NN * NP * 2);
    const float4* gD = (const float4*)(Ds + (size_t)b * NN * NP * 2);
    #pragma unroll
    for (int r = 0; r < 4; ++r) {
        const int m   = t + 256 * r;               // float4 index 0..1023
        const int off = (m >> 3) * STRIDE + (m & 7) * 4;
        *(float4*)(sB + off) = gB[m];
        *(float4*)(sD + off) = gD[m];
    }
    __syncthreads();

    // ---- in-block w2: thread t handles n = t&127, half of the j range ----
    {
        const int n  = t & 127;
        const int jh = t >> 7;          // 0 or 1
        const float4* B4 = (const float4*)(sB + n * STRIDE);
        const float4* D4 = (const float4*)(sD + n * STRIDE);
        float b0[NP], b1[NP];
        #pragma unroll
        for (int q = 0; q < 8; ++q) {
            const float4 f = B4[q];
            b0[2 * q] = f.x; b1[2 * q] = f.y;
            b0[2 * q + 1] = f.z; b1[2 * q + 1] = f.w;
        }
        float w = 0.0f;                 // relu(min) == min(relu): monotone commute
        #pragma unroll
        for (int qq = 0; qq < 4; ++qq) {
            const float4 fd = D4[jh * 4 + qq];
            #pragma unroll
            for (int i = 0; i < NP; ++i) {
                w = fmaxf(w, fmaxf(fminf(fd.x - b0[i], fd.y - b1[i]), 0.0f));
                w = fmaxf(w, fmaxf(fminf(fd.z - b0[i], fd.w - b1[i]), 0.0f));
            }
        }
        wp[jh][n] = w;
    }
    __syncthreads();
    if (t < NN) {
        float wv = fmaxf(wp[0][t], wp[1][t]);
        if (!isfinite(wv)) wv = 0.0f;
        sW2[t] = wv * wv;
    }
    __syncthreads();

    // ---- thread mapping: 8 point-groups (4 pts each) x 32 n-chunks (4 n each) ----
    const int g  = t & 7;                   // point group
    const int c  = t >> 3;                  // n-chunk
    const int p0 = pblk * PTS_PER_BLK + 4 * g;
    const int i0 = p0 >> 6;                 // block-uniform row -> uniform x0
    const float x0 = -3.0f + 6.0f * (float)i0 / 63.0f;
    float x1v[4];
    #pragma unroll
    for (int j = 0; j < 4; ++j)
        x1v[j] = -3.0f + 6.0f * (float)((p0 + j) & 63) / 63.0f;

    const float cexp = -0.5f / (0.3f * 0.3f);
    float acc[4] = {0.0f, 0.0f, 0.0f, 0.0f};

    for (int k = 0; k < 4; ++k) {
        const int n = c + 32 * k;           // wave's 8 chunks -> 8 bank groups, bcast x8
        const float4* B4 = (const float4*)(sB + n * STRIDE);
        const float4* D4 = (const float4*)(sD + n * STRIDE);
        float db[4] = {1e30f, 1e30f, 1e30f, 1e30f};
        float dd[4] = {1e30f, 1e30f, 1e30f, 1e30f};
        #pragma unroll
        for (int q = 0; q < 8; ++q) {       // 2 boundary points per float4
            const float4 fb = B4[q];
            const float4 fd = D4[q];
            float s  = fb.x - x0;           // shared across the 4 grid points
            float sd = x0 - fd.x;
            #pragma unroll
            for (int j = 0; j < 4; ++j) {
                db[j] = fminf(db[j], fmaxf(s,  fb.y - x1v[j]));
                dd[j] = fminf(dd[j], fmaxf(sd, x1v[j] - fd.y));
            }
            s  = fb.z - x0;
            sd = x0 - fd.z;
            #pragma unroll
            for (int j = 0; j < 4; ++j) {
                db[j] = fminf(db[j], fmaxf(s,  fb.w - x1v[j]));
                dd[j] = fminf(dd[j], fmaxf(sd, x1v[j] - fd.w));
            }
        }
        const float w2n = sW2[n];
        #pragma unroll
        for (int j = 0; j < 4; ++j) {
            const float r = fmaxf(fmaxf(db[j], dd[j]), 0.0f);
            acc[j] = fmaf(__expf(cexp * r * r), w2n, acc[j]);
        }
    }

    #pragma unroll
    for (int j = 0; j < 4; ++j) psum[c][4 * g + j] = acc[j];
    __syncthreads();
    if (t < PTS_PER_BLK) {
        float s = 0.0f;
        #pragma unroll
        for (int q = 0; q < NCHUNK; ++q) s += psum[q][t];
        out[(size_t)b * NPTS + pblk * PTS_PER_BLK + t] = s;
    }
}

extern "C" void kernel_launch(void* const* d_in, const int* in_sizes, int n_in,
                              void* d_out, int out_size, void* d_ws, size_t ws_size,
                              hipStream_t stream) {
    const float* Bs = (const float*)d_in[0];
    const float* Ds = (const float*)d_in[1];
    float* out = (float*)d_out;
    fused_kernel<<<dim3(NB * (NPTS / PTS_PER_BLK)), dim3(256), 0, stream>>>(Bs, Ds, out);
}